// Round 13
// baseline (43.659 us; speedup 1.0000x reference)
//
#include <hip/hip_runtime.h>
#include <math.h>

#define GAMMA 0.3f      // NUM_BASIS / MAX_RADIUS = 3/10

typedef __bf16 bf16x8 __attribute__((ext_vector_type(8)));
typedef __bf16 bf16x4 __attribute__((ext_vector_type(4)));
typedef float  f32x4  __attribute__((ext_vector_type(4)));

// ---------------------------------------------------------------------------
// K1: W[z,b,h,i] = sum_j x[z,b,j] * rw2[h, i*32+j] via MFMA, computed ONCE.
// Layout: Wg[(((z*16+bc)*100 + h)*32 + i)*16 + b_local]  (b fastest, 16/h-row)
//   -> any h-slice is contiguous; k2 B-frag = 2x ds_read_b64 (h0,h1 rows).
// grid 1600 = (z*16+bc)(64) x nq(25); 256 thr = 4 waves; wave w: n-tiles nq*8+w*2+{0,1}
// MFMA 16x16x32 bf16 frags: A[m=l&15][k=(l>>4)*4+e, +16]; B[k][n=l&15];
//   D col=l&15, row=(l>>4)*4+r   (learn_hip m89-verified)
// ---------------------------------------------------------------------------
__global__ __launch_bounds__(256) void k1_W(const float* __restrict__ x,
                                            const float* __restrict__ rw2,
                                            __bf16* __restrict__ Wg) {
    int bid = blockIdx.x;
    int mt = bid / 25, nq = bid % 25;
    int z = mt >> 4, bc = mt & 15;
    int t = threadIdx.x, w = t >> 6, l = t & 63;
    int l16 = l & 15, lg = l >> 4;

    // A-frag: A[m=l16][k=lg*4+e (+16)] = x[z, bc*16+m, j=k]
    int row = (z * 256 + bc * 16 + l16) * 32;
    float4 v0 = *(const float4*)(x + row + lg * 4);
    float4 v1 = *(const float4*)(x + row + lg * 4 + 16);
    bf16x8 xa;
    xa[0] = (__bf16)v0.x; xa[1] = (__bf16)v0.y; xa[2] = (__bf16)v0.z; xa[3] = (__bf16)v0.w;
    xa[4] = (__bf16)v1.x; xa[5] = (__bf16)v1.y; xa[6] = (__bf16)v1.z; xa[7] = (__bf16)v1.w;

    #pragma unroll
    for (int q = 0; q < 2; ++q) {
        int nt = nq * 8 + w * 2 + q;          // 0..199 = 100 h x 2 i-tiles
        int h = nt >> 1;
        int icol = ((nt & 1) << 4) + l16;     // i = 0..31
        const float* rp = rw2 + h * 1024 + icol * 32 + lg * 4;
        float4 r0 = *(const float4*)rp;
        float4 r1 = *(const float4*)(rp + 16);
        bf16x8 rb;
        rb[0] = (__bf16)r0.x; rb[1] = (__bf16)r0.y; rb[2] = (__bf16)r0.z; rb[3] = (__bf16)r0.w;
        rb[4] = (__bf16)r1.x; rb[5] = (__bf16)r1.y; rb[6] = (__bf16)r1.z; rb[7] = (__bf16)r1.w;
        f32x4 d = {0.f, 0.f, 0.f, 0.f};
        d = __builtin_amdgcn_mfma_f32_16x16x32_bf16(xa, rb, d, 0, 0, 0);
        // D row r = b_local lg*4+r; write 4 contiguous b's of row (h, icol)
        bf16x4 pk;
        pk[0] = (__bf16)d[0]; pk[1] = (__bf16)d[1]; pk[2] = (__bf16)d[2]; pk[3] = (__bf16)d[3];
        size_t off = (((size_t)(z * 16 + bc) * 100 + h) * 32 + icol) * 16 + lg * 4;
        *(bf16x4*)(Wg + off) = pk;
    }
}

// ---------------------------------------------------------------------------
// K2: grid 1024 = z(4) x bc(16) x hh(4) x ah(4); 256 thr = 4 waves.
// Block: a in [ah*64,+64), b in [bc*16,+16), h in [hh*25,+25).
// NO W computation: stages its 25.6 KB Wg slice (reg-staged, loads issued
// before bas-exp math so HBM latency hides under it). LDS 26.8 KB ->
// 4 blocks/CU x 4 waves = 16 waves/CU = 4 waves/SIMD.
// Phase C: wave w owns a-tile w (16 a); 12 k-steps (2h x 16b) + odd-h epilogue;
// B-frag = 2x ds_read_b64 (rows h0,h1 of LDS [h][i][b]).
// ---------------------------------------------------------------------------
__global__ __launch_bounds__(256, 4) void k2_main(const __bf16* __restrict__ Wg,
                                                  const float* __restrict__ xyz,
                                                  const float* __restrict__ rw1,
                                                  float* __restrict__ part) {
    __shared__ __bf16 Wlds[12800];     // [25 h][32 i][16 b] = 25,600 B
    __shared__ float  rw1s[304];       //  1,216 B

    int bid = blockIdx.x;
    int ah = bid & 3;
    int hh = (bid >> 2) & 3;
    int bc = (bid >> 4) & 15;
    int z  = bid >> 8;
    int t  = threadIdx.x;
    int w  = t >> 6;              // 0..3 = a-tile
    int l  = t & 63;
    int l16 = l & 15, lg = l >> 4;

    for (int e = t; e < 300; e += 256) rw1s[e] = rw1[e];

    // ---- issue slice loads early (1600 uint4 chunks over 256 threads) ----
    const uint4* gs = (const uint4*)(Wg + ((size_t)(z * 16 + bc) * 51200 + (size_t)hh * 12800));
    uint4 stg[7];
    #pragma unroll
    for (int j = 0; j < 6; ++j) stg[j] = gs[t + j * 256];
    if (t < 64) stg[6] = gs[t + 1536];

    // ---- phase A (overlaps load latency): bas regs, a = l16 of a-tile w ----
    int a_glob = ah * 64 + w * 16 + l16;
    float ax = xyz[(z * 256 + a_glob) * 3 + 0];
    float ay = xyz[(z * 256 + a_glob) * 3 + 1];
    float az = xyz[(z * 256 + a_glob) * 3 + 2];
    float bas[4][3];
    #pragma unroll
    for (int e = 0; e < 4; ++e) {
        int b_glob = bc * 16 + lg * 4 + e;
        float dx = xyz[(z * 256 + b_glob) * 3 + 0] - ax;
        float dy = xyz[(z * 256 + b_glob) * 3 + 1] - ay;
        float dz = xyz[(z * 256 + b_glob) * 3 + 2] - az;
        float r  = sqrtf(dx * dx + dy * dy + dz * dz + 1e-12f);
        float r5 = r - 5.f, r10 = r - 10.f;
        bas[e][0] = __expf(-GAMMA * r * r);
        bas[e][1] = __expf(-GAMMA * r5 * r5);
        bas[e][2] = __expf(-GAMMA * r10 * r10);
    }

    // ---- write staged slice to LDS ----
    #pragma unroll
    for (int j = 0; j < 6; ++j) ((uint4*)Wlds)[t + j * 256] = stg[j];
    if (t < 64) ((uint4*)Wlds)[t + 1536] = stg[6];
    __syncthreads();

    // ---- phase C: 12 full k-steps + epilogue (h_loc = 24) ----
    f32x4 acc0 = {0.f, 0.f, 0.f, 0.f};
    f32x4 acc1 = {0.f, 0.f, 0.f, 0.f};
    for (int ks = 0; ks < 12; ++ks) {
        int h0g = hh * 25 + 2 * ks;
        float u00 = rw1s[h0g],       u01 = rw1s[h0g + 1];
        float u10 = rw1s[100 + h0g], u11 = rw1s[101 + h0g];
        float u20 = rw1s[200 + h0g], u21 = rw1s[201 + h0g];
        bf16x8 af;
        #pragma unroll
        for (int e = 0; e < 4; ++e) {
            float p0 = bas[e][0] * u00 + bas[e][1] * u10 + bas[e][2] * u20;
            float p1 = bas[e][0] * u01 + bas[e][1] * u11 + bas[e][2] * u21;
            float s0 = p0 * __builtin_amdgcn_rcpf(1.f + __expf(-p0));   // swish
            float s1 = p1 * __builtin_amdgcn_rcpf(1.f + __expf(-p1));
            af[e]     = (__bf16)s0;    // k = lg*4+e      (h0, b-block)
            af[e + 4] = (__bf16)s1;    // k = lg*4+e+16   (h1)
        }
        int b0 = (2 * ks) * 512 + l16 * 16 + lg * 4;   // [h0][icol=l16][b=lg*4]
        bf16x4 a0 = *(const bf16x4*)&Wlds[b0];
        bf16x4 a1 = *(const bf16x4*)&Wlds[b0 + 512];          // h1 row
        bf16x4 c0 = *(const bf16x4*)&Wlds[b0 + 256];          // icol = l16+16
        bf16x4 c1 = *(const bf16x4*)&Wlds[b0 + 512 + 256];
        bf16x8 bf0 = __builtin_shufflevector(a0, a1, 0, 1, 2, 3, 4, 5, 6, 7);
        bf16x8 bf1 = __builtin_shufflevector(c0, c1, 0, 1, 2, 3, 4, 5, 6, 7);
        acc0 = __builtin_amdgcn_mfma_f32_16x16x32_bf16(af, bf0, acc0, 0, 0, 0);
        acc1 = __builtin_amdgcn_mfma_f32_16x16x32_bf16(af, bf1, acc1, 0, 0, 0);
    }
    {   // epilogue: h_loc = 24 alone; odd half zero on A and B
        int h0g = hh * 25 + 24;
        float u00 = rw1s[h0g], u10 = rw1s[100 + h0g], u20 = rw1s[200 + h0g];
        bf16x8 af;
        #pragma unroll
        for (int e = 0; e < 4; ++e) {
            float p0 = bas[e][0] * u00 + bas[e][1] * u10 + bas[e][2] * u20;
            float s0 = p0 * __builtin_amdgcn_rcpf(1.f + __expf(-p0));
            af[e]     = (__bf16)s0;
            af[e + 4] = (__bf16)0.f;
        }
        bf16x4 zz = {(__bf16)0.f, (__bf16)0.f, (__bf16)0.f, (__bf16)0.f};
        int b0 = 24 * 512 + l16 * 16 + lg * 4;
        bf16x4 a0 = *(const bf16x4*)&Wlds[b0];
        bf16x4 c0 = *(const bf16x4*)&Wlds[b0 + 256];
        bf16x8 bf0 = __builtin_shufflevector(a0, zz, 0, 1, 2, 3, 4, 5, 6, 7);
        bf16x8 bf1 = __builtin_shufflevector(c0, zz, 0, 1, 2, 3, 4, 5, 6, 7);
        acc0 = __builtin_amdgcn_mfma_f32_16x16x32_bf16(af, bf0, acc0, 0, 0, 0);
        acc1 = __builtin_amdgcn_mfma_f32_16x16x32_bf16(af, bf1, acc1, 0, 0, 0);
    }

    // ---- write partials: chunk qc = bc*4+hh; D row r -> a = a-tile + lg*4+r ----
    int qc = bc * 4 + hh;
    #pragma unroll
    for (int r = 0; r < 4; ++r) {
        int a = ah * 64 + w * 16 + lg * 4 + r;
        size_t base = ((size_t)(z * 64 + qc) * 256 + a) * 32;
        part[base + l16]      = acc0[r];
        part[base + 16 + l16] = acc1[r];
    }
}

// ---------------------------------------------------------------------------
// K3a: sum over 64 chunks (unroll-8 for outstanding loads), abs+mask+scale,
// pool 4 a's per block. grid 256 = z(4) x ag(64); 256 thr.
// ---------------------------------------------------------------------------
__global__ __launch_bounds__(256) void k3a_reduce(const float* __restrict__ part,
                                                  const int* __restrict__ mask,
                                                  float* __restrict__ pooled_part) {
    int blk = blockIdx.x;
    int z = blk >> 6, ag = blk & 63;
    int t = threadIdx.x;
    int i = t & 31;
    int qg = (t >> 5) & 1;
    int a_loc = t >> 6;               // 0..3
    int a = ag * 4 + a_loc;
    const float* base = part + ((size_t)z * 64 * 256 + (size_t)a) * 32 + i;
    float s = 0.f;
    #pragma unroll 8
    for (int q = qg; q < 64; q += 2)
        s += base[(size_t)q * 8192];
    __shared__ float buf[4][2][32];
    buf[a_loc][qg][i] = s;
    __syncthreads();
    if (t < 128) {
        int al = t >> 5, ii = t & 31;
        float v = buf[al][0][ii] + buf[al][1][ii];
        float sc = (mask[z * 256 + ag * 4 + al] != 0) ? 0.0625f : 0.f;   // 1/sqrt(256)
        buf[al][0][ii] = fabsf(v) * sc;
    }
    __syncthreads();
    if (t < 32) {
        float v = buf[0][0][t] + buf[1][0][t] + buf[2][0][t] + buf[3][0][t];
        pooled_part[(z * 64 + ag) * 32 + t] = v;
    }
}

// ---------------------------------------------------------------------------
// K3b: pool over ag(64) (unroll-8), normalize (ddof=1), fc3+leaky, fc2 -> out
// ---------------------------------------------------------------------------
__global__ __launch_bounds__(128) void k3b_final(const float* __restrict__ pooled_part,
                                                 const float* __restrict__ fc3_w,
                                                 const float* __restrict__ fc3_b,
                                                 const float* __restrict__ fc2_w,
                                                 const float* __restrict__ fc2_b,
                                                 float* __restrict__ out) {
    int t = threadIdx.x;
    int z = t >> 5, i = t & 31;
    float s = 0.f;
    #pragma unroll 8
    for (int ag = 0; ag < 64; ++ag) s += pooled_part[(z * 64 + ag) * 32 + i];
    float sm = s;
    #pragma unroll
    for (int off = 16; off; off >>= 1) sm += __shfl_xor(sm, off, 32);
    float mean = sm * (1.f / 32.f);
    float d = s - mean;
    float ss = d * d;
    #pragma unroll
    for (int off = 16; off; off >>= 1) ss += __shfl_xor(ss, off, 32);
    float stdv = sqrtf(ss * (1.f / 31.f));   // ddof=1
    float nv = d / (stdv + 1e-6f);
    __shared__ float pn[4][32];
    pn[z][i] = nv;
    __syncthreads();
    float h1 = fc3_b[i];
    #pragma unroll
    for (int j = 0; j < 32; ++j) h1 += pn[z][j] * fc3_w[j * 32 + i];
    h1 = (h1 >= 0.f) ? h1 : 0.01f * h1;
    float y = h1 * fc2_w[i];
    #pragma unroll
    for (int off = 16; off; off >>= 1) y += __shfl_xor(y, off, 32);
    if (i == 0) out[z] = y + fc2_b[0];
}

extern "C" void kernel_launch(void* const* d_in, const int* in_sizes, int n_in,
                              void* d_out, int out_size, void* d_ws, size_t ws_size,
                              hipStream_t stream) {
    const float* x    = (const float*)d_in[0];
    const float* xyz  = (const float*)d_in[1];
    const int*   mask = (const int*)d_in[2];
    const float* rw1  = (const float*)d_in[3];
    const float* rw2  = (const float*)d_in[4];
    const float* fc3w = (const float*)d_in[5];
    const float* fc3b = (const float*)d_in[6];
    const float* fc2w = (const float*)d_in[7];
    const float* fc2b = (const float*)d_in[8];
    float* out = (float*)d_out;

    __bf16* Wg         = (__bf16*)d_ws;                              // 6,553,600 B
    float*  part       = (float*)((char*)d_ws + 6553600);            // 8,388,608 B
    float*  pooled_part= (float*)((char*)d_ws + 6553600 + 8388608);  //    32,768 B

    hipLaunchKernelGGL(k1_W,       dim3(1600), dim3(256), 0, stream, x, rw2, Wg);
    hipLaunchKernelGGL(k2_main,    dim3(1024), dim3(256), 0, stream, Wg, xyz, rw1, part);
    hipLaunchKernelGGL(k3a_reduce, dim3(256),  dim3(256), 0, stream, part, mask, pooled_part);
    hipLaunchKernelGGL(k3b_final,  dim3(1),    dim3(128), 0, stream, pooled_part, fc3w, fc3b, fc2w, fc2b, out);
}

// Round 14
// 35.923 us; speedup vs baseline: 1.2154x; 1.2154x over previous
//
#include <hip/hip_runtime.h>
#include <math.h>

#define GAMMA 0.3f      // NUM_BASIS / MAX_RADIUS = 3/10
#define WSTR  1608      // Wlds row stride in bf16 elems (1600 + 8 pad)

typedef __bf16 bf16x8 __attribute__((ext_vector_type(8)));
typedef __bf16 bf16x4 __attribute__((ext_vector_type(4)));
typedef float  f32x4  __attribute__((ext_vector_type(4)));

// ---------------------------------------------------------------------------
// K2 (round-7 proven config, atomic epilogue): grid 256 = z(4) x bc(16) x ac(4);
// 512 threads = 8 waves. wave w: wa = w>>1 (16-a subtile), wk = w&1 (h-half).
// Phase B: W[b,h,i] = x·rw2 via MFMA -> LDS bf16 [i][k=h*16+b] (8w x 25 n-tiles)
// Phase C: 25 MFMA k-steps/wave, swish A-frag in-register
// Epilogue: combine wk halves via LDS; wk==0 waves atomicAdd into part[z][a][i]
//   (16 bc-blocks accumulate into the same 128 KB array; f32 atomics, L2-side)
// MFMA 16x16x32 bf16 frags: A[m=l&15][k=(l>>4)*4+e, +16]; B[k][n=l&15];
//   D col=l&15, row=(l>>4)*4+r   (learn_hip m89-verified)
// ---------------------------------------------------------------------------
__global__ __launch_bounds__(512) void k2_fused(const float* __restrict__ x,
                                                const float* __restrict__ xyz,
                                                const float* __restrict__ rw1,
                                                const float* __restrict__ rw2,
                                                float* __restrict__ part) {
    extern __shared__ char smem[];
    __bf16* Wlds = (__bf16*)smem;                          // [32][WSTR]  102,912 B
    float*  rw1s = (float*)(smem + 32 * WSTR * 2);         // [304]         1,216 B
    float (*red)[2][16][17] = (float(*)[2][16][17])(smem + 32 * WSTR * 2 + 1216); // 8,704 B

    int bid = blockIdx.x;
    int ac = bid & 3;
    int bc = (bid >> 2) & 15;
    int z  = bid >> 6;
    int t  = threadIdx.x;
    int w  = t >> 6;              // 0..7
    int wa = w >> 1, wk = w & 1;
    int l  = t & 63;
    int l16 = l & 15, lg = l >> 4;

    for (int e = t; e < 300; e += 512) rw1s[e] = rw1[e];

    // ---- phase A: per-lane bas registers: a-row = l16 (of wa subtile), b = lg*4+e ----
    int a_glob = ac * 64 + wa * 16 + l16;
    float ax = xyz[(z * 256 + a_glob) * 3 + 0];
    float ay = xyz[(z * 256 + a_glob) * 3 + 1];
    float az = xyz[(z * 256 + a_glob) * 3 + 2];
    float bas[4][3];
    #pragma unroll
    for (int e = 0; e < 4; ++e) {
        int b_glob = bc * 16 + lg * 4 + e;
        float dx = xyz[(z * 256 + b_glob) * 3 + 0] - ax;
        float dy = xyz[(z * 256 + b_glob) * 3 + 1] - ay;
        float dz = xyz[(z * 256 + b_glob) * 3 + 2] - az;
        float r  = sqrtf(dx * dx + dy * dy + dz * dz + 1e-12f);
        float r5 = r - 5.f, r10 = r - 10.f;
        bas[e][0] = __expf(-GAMMA * r * r);
        bas[e][1] = __expf(-GAMMA * r5 * r5);
        bas[e][2] = __expf(-GAMMA * r10 * r10);
    }

    // ---- phase B: W chunk via MFMA (M=16 b, N=3200 hi, K=32 j), 25 n-tiles/wave ----
    bf16x8 xa;
    {
        int row = (z * 256 + bc * 16 + l16) * 32;
        float4 v0 = *(const float4*)(x + row + lg * 4);
        float4 v1 = *(const float4*)(x + row + lg * 4 + 16);
        xa[0] = (__bf16)v0.x; xa[1] = (__bf16)v0.y; xa[2] = (__bf16)v0.z; xa[3] = (__bf16)v0.w;
        xa[4] = (__bf16)v1.x; xa[5] = (__bf16)v1.y; xa[6] = (__bf16)v1.z; xa[7] = (__bf16)v1.w;
    }
    for (int q = 0; q < 25; ++q) {
        int nt = w * 25 + q;                 // 0..199
        int h  = nt >> 1;
        int icol = ((nt & 1) << 4) + l16;    // i = 0..31
        const float* rp = rw2 + h * 1024 + icol * 32 + lg * 4;
        float4 r0 = *(const float4*)rp;
        float4 r1 = *(const float4*)(rp + 16);
        bf16x8 rb;
        rb[0] = (__bf16)r0.x; rb[1] = (__bf16)r0.y; rb[2] = (__bf16)r0.z; rb[3] = (__bf16)r0.w;
        rb[4] = (__bf16)r1.x; rb[5] = (__bf16)r1.y; rb[6] = (__bf16)r1.z; rb[7] = (__bf16)r1.w;
        f32x4 d = {0.f, 0.f, 0.f, 0.f};
        d = __builtin_amdgcn_mfma_f32_16x16x32_bf16(xa, rb, d, 0, 0, 0);
        bf16x4 pk;
        pk[0] = (__bf16)d[0]; pk[1] = (__bf16)d[1]; pk[2] = (__bf16)d[2]; pk[3] = (__bf16)d[3];
        *(bf16x4*)&Wlds[icol * WSTR + h * 16 + lg * 4] = pk;
    }
    __syncthreads();

    // ---- phase C: 25 MFMA k-steps over this wave's h-half (k = h*16+b) ----
    f32x4 acc0 = {0.f, 0.f, 0.f, 0.f};
    f32x4 acc1 = {0.f, 0.f, 0.f, 0.f};
    for (int ks = 0; ks < 25; ++ks) {
        int hp = wk * 25 + ks;               // h-pair index 0..49
        int h0 = 2 * hp, h1 = h0 + 1;
        float u00 = rw1s[h0],       u01 = rw1s[h1];
        float u10 = rw1s[100 + h0], u11 = rw1s[100 + h1];
        float u20 = rw1s[200 + h0], u21 = rw1s[200 + h1];
        bf16x8 af;
        #pragma unroll
        for (int e = 0; e < 4; ++e) {
            float p0 = bas[e][0] * u00 + bas[e][1] * u10 + bas[e][2] * u20;
            float p1 = bas[e][0] * u01 + bas[e][1] * u11 + bas[e][2] * u21;
            float s0 = p0 * __builtin_amdgcn_rcpf(1.f + __expf(-p0));   // swish
            float s1 = p1 * __builtin_amdgcn_rcpf(1.f + __expf(-p1));
            af[e]     = (__bf16)s0;    // k = lg*4+e      (h0, even)
            af[e + 4] = (__bf16)s1;    // k = lg*4+e+16   (h1, odd)
        }
        int kb = hp * 32 + lg * 4;
        const __bf16* w0 = &Wlds[l16 * WSTR + kb];
        const __bf16* w1 = w0 + 16 * WSTR;
        bf16x4 b0l = *(const bf16x4*)w0, b0h = *(const bf16x4*)(w0 + 16);
        bf16x4 b1l = *(const bf16x4*)w1, b1h = *(const bf16x4*)(w1 + 16);
        bf16x8 bf0 = __builtin_shufflevector(b0l, b0h, 0, 1, 2, 3, 4, 5, 6, 7);
        bf16x8 bf1 = __builtin_shufflevector(b1l, b1h, 0, 1, 2, 3, 4, 5, 6, 7);
        acc0 = __builtin_amdgcn_mfma_f32_16x16x32_bf16(af, bf0, acc0, 0, 0, 0);
        acc1 = __builtin_amdgcn_mfma_f32_16x16x32_bf16(af, bf1, acc1, 0, 0, 0);
    }

    // ---- epilogue: combine wk halves via LDS, atomicAdd into part[z][a][i] ----
    if (wk == 1) {
        #pragma unroll
        for (int r = 0; r < 4; ++r) {
            red[wa][0][lg * 4 + r][l16] = acc0[r];
            red[wa][1][lg * 4 + r][l16] = acc1[r];
        }
    }
    __syncthreads();
    if (wk == 0) {
        #pragma unroll
        for (int r = 0; r < 4; ++r) {
            float v0 = acc0[r] + red[wa][0][lg * 4 + r][l16];
            float v1 = acc1[r] + red[wa][1][lg * 4 + r][l16];
            int a = ac * 64 + wa * 16 + lg * 4 + r;
            float* cell = &part[(size_t)(z * 256 + a) * 32];
            atomicAdd(cell + l16,      v0);
            atomicAdd(cell + 16 + l16, v1);
        }
    }
}

// ---------------------------------------------------------------------------
// K3: one block per z (grid 4, 256 threads). Reads part[z] (32 KB),
// abs+mask+scale, pool over a, normalize (ddof=1), fc3+leaky, fc2 -> out[z].
// ---------------------------------------------------------------------------
__global__ __launch_bounds__(256) void k3_final(const float* __restrict__ part,
                                                const int* __restrict__ mask,
                                                const float* __restrict__ fc3_w,
                                                const float* __restrict__ fc3_b,
                                                const float* __restrict__ fc2_w,
                                                const float* __restrict__ fc2_b,
                                                float* __restrict__ out) {
    __shared__ float pool[8][33];
    __shared__ float pn[32];
    int z = blockIdx.x;
    int t = threadIdx.x;
    int i = t & 31, g = t >> 5;          // g = 0..7, 32 a's each
    float s = 0.f;
    #pragma unroll 8
    for (int al = 0; al < 32; ++al) {
        int a = g * 32 + al;
        float v = part[(size_t)(z * 256 + a) * 32 + i];
        float sc = (mask[z * 256 + a] != 0) ? 0.0625f : 0.f;   // 1/sqrt(256)
        s += fabsf(v) * sc;
    }
    pool[g][i] = s;
    __syncthreads();
    if (t < 32) {
        float p = 0.f;
        #pragma unroll
        for (int q = 0; q < 8; ++q) p += pool[q][t];
        float sm = p;
        #pragma unroll
        for (int off = 16; off; off >>= 1) sm += __shfl_xor(sm, off, 32);
        float mean = sm * (1.f / 32.f);
        float d = p - mean;
        float ss = d * d;
        #pragma unroll
        for (int off = 16; off; off >>= 1) ss += __shfl_xor(ss, off, 32);
        float stdv = sqrtf(ss * (1.f / 31.f));   // ddof=1
        pn[t] = d / (stdv + 1e-6f);
    }
    __syncthreads();
    if (t < 32) {
        float h1 = fc3_b[t];
        #pragma unroll
        for (int j = 0; j < 32; ++j) h1 += pn[j] * fc3_w[j * 32 + t];
        h1 = (h1 >= 0.f) ? h1 : 0.01f * h1;
        float y = h1 * fc2_w[t];
        #pragma unroll
        for (int off = 16; off; off >>= 1) y += __shfl_xor(y, off, 32);
        if (t == 0) out[z] = y + fc2_b[0];
    }
}

extern "C" void kernel_launch(void* const* d_in, const int* in_sizes, int n_in,
                              void* d_out, int out_size, void* d_ws, size_t ws_size,
                              hipStream_t stream) {
    const float* x    = (const float*)d_in[0];
    const float* xyz  = (const float*)d_in[1];
    const int*   mask = (const int*)d_in[2];
    const float* rw1  = (const float*)d_in[3];
    const float* rw2  = (const float*)d_in[4];
    const float* fc3w = (const float*)d_in[5];
    const float* fc3b = (const float*)d_in[6];
    const float* fc2w = (const float*)d_in[7];
    const float* fc2b = (const float*)d_in[8];
    float* out = (float*)d_out;

    float* part = (float*)d_ws;          // 4z * 256a * 32i * 4B = 131,072 B

    const int LDS_BYTES = 32 * WSTR * 2 + 1216 + 8704;      // 112,832

    hipMemsetAsync(part, 0, 131072, stream);                // zero accumulator each call
    hipLaunchKernelGGL(k2_fused, dim3(256), dim3(512), LDS_BYTES, stream,
                       x, xyz, rw1, rw2, part);
    hipLaunchKernelGGL(k3_final, dim3(4), dim3(256), 0, stream,
                       part, mask, fc3w, fc3b, fc2w, fc2b, out);
}

// Round 15
// 35.102 us; speedup vs baseline: 1.2438x; 1.0234x over previous
//
#include <hip/hip_runtime.h>
#include <math.h>

#define GAMMA 0.3f      // NUM_BASIS / MAX_RADIUS = 3/10
#define WSTR  1608      // Wlds row stride in bf16 elems (1600 + 8 pad)

typedef __bf16 bf16x8 __attribute__((ext_vector_type(8)));
typedef __bf16 bf16x4 __attribute__((ext_vector_type(4)));
typedef float  f32x4  __attribute__((ext_vector_type(4)));

// ---------------------------------------------------------------------------
// K2 (round-7/14 proven config + register fix): grid 256 = z(4) x bc(16) x ac(4);
// 512 threads = 8 waves. wave w: wa = w>>1 (16-a subtile), wk = w&1 (h-half).
// __launch_bounds__(512, 2): we run exactly 2 waves/EU (1 block/CU, 112KB LDS),
// so let the allocator use up to ~128 VGPRs — the prior build was capped at 32
// (compiler can't see dynamic LDS -> assumed 8 waves/EU) which serialized every
// L2 load and swish chain.
// Phase B: W[b,h,i] = x·rw2 via MFMA -> LDS bf16 [i][k=h*16+b] (8w x 25 n-tiles)
// Phase C: 25 MFMA k-steps/wave, swish A-frag in-register
// Epilogue: combine wk halves via LDS; wk==0 waves atomicAdd into part[z][a][i]
// MFMA 16x16x32 bf16 frags: A[m=l&15][k=(l>>4)*4+e, +16]; B[k][n=l&15];
//   D col=l&15, row=(l>>4)*4+r   (learn_hip m89-verified)
// ---------------------------------------------------------------------------
__global__ __launch_bounds__(512, 2) void k2_fused(const float* __restrict__ x,
                                                   const float* __restrict__ xyz,
                                                   const float* __restrict__ rw1,
                                                   const float* __restrict__ rw2,
                                                   float* __restrict__ part) {
    extern __shared__ char smem[];
    __bf16* Wlds = (__bf16*)smem;                          // [32][WSTR]  102,912 B
    float*  rw1s = (float*)(smem + 32 * WSTR * 2);         // [304]         1,216 B
    float (*red)[2][16][17] = (float(*)[2][16][17])(smem + 32 * WSTR * 2 + 1216); // 8,704 B

    int bid = blockIdx.x;
    int ac = bid & 3;
    int bc = (bid >> 2) & 15;
    int z  = bid >> 6;
    int t  = threadIdx.x;
    int w  = t >> 6;              // 0..7
    int wa = w >> 1, wk = w & 1;
    int l  = t & 63;
    int l16 = l & 15, lg = l >> 4;

    for (int e = t; e < 300; e += 512) rw1s[e] = rw1[e];

    // ---- phase A: per-lane bas registers: a-row = l16 (of wa subtile), b = lg*4+e ----
    int a_glob = ac * 64 + wa * 16 + l16;
    float ax = xyz[(z * 256 + a_glob) * 3 + 0];
    float ay = xyz[(z * 256 + a_glob) * 3 + 1];
    float az = xyz[(z * 256 + a_glob) * 3 + 2];
    float bas[4][3];
    #pragma unroll
    for (int e = 0; e < 4; ++e) {
        int b_glob = bc * 16 + lg * 4 + e;
        float dx = xyz[(z * 256 + b_glob) * 3 + 0] - ax;
        float dy = xyz[(z * 256 + b_glob) * 3 + 1] - ay;
        float dz = xyz[(z * 256 + b_glob) * 3 + 2] - az;
        float r  = sqrtf(dx * dx + dy * dy + dz * dz + 1e-12f);
        float r5 = r - 5.f, r10 = r - 10.f;
        bas[e][0] = __expf(-GAMMA * r * r);
        bas[e][1] = __expf(-GAMMA * r5 * r5);
        bas[e][2] = __expf(-GAMMA * r10 * r10);
    }

    // ---- phase B: W chunk via MFMA (M=16 b, N=3200 hi, K=32 j), 25 n-tiles/wave ----
    bf16x8 xa;
    {
        int row = (z * 256 + bc * 16 + l16) * 32;
        float4 v0 = *(const float4*)(x + row + lg * 4);
        float4 v1 = *(const float4*)(x + row + lg * 4 + 16);
        xa[0] = (__bf16)v0.x; xa[1] = (__bf16)v0.y; xa[2] = (__bf16)v0.z; xa[3] = (__bf16)v0.w;
        xa[4] = (__bf16)v1.x; xa[5] = (__bf16)v1.y; xa[6] = (__bf16)v1.z; xa[7] = (__bf16)v1.w;
    }
    #pragma unroll 2
    for (int q = 0; q < 25; ++q) {
        int nt = w * 25 + q;                 // 0..199
        int h  = nt >> 1;
        int icol = ((nt & 1) << 4) + l16;    // i = 0..31
        const float* rp = rw2 + h * 1024 + icol * 32 + lg * 4;
        float4 r0 = *(const float4*)rp;
        float4 r1 = *(const float4*)(rp + 16);
        bf16x8 rb;
        rb[0] = (__bf16)r0.x; rb[1] = (__bf16)r0.y; rb[2] = (__bf16)r0.z; rb[3] = (__bf16)r0.w;
        rb[4] = (__bf16)r1.x; rb[5] = (__bf16)r1.y; rb[6] = (__bf16)r1.z; rb[7] = (__bf16)r1.w;
        f32x4 d = {0.f, 0.f, 0.f, 0.f};
        d = __builtin_amdgcn_mfma_f32_16x16x32_bf16(xa, rb, d, 0, 0, 0);
        bf16x4 pk;
        pk[0] = (__bf16)d[0]; pk[1] = (__bf16)d[1]; pk[2] = (__bf16)d[2]; pk[3] = (__bf16)d[3];
        *(bf16x4*)&Wlds[icol * WSTR + h * 16 + lg * 4] = pk;
    }
    __syncthreads();

    // ---- phase C: 25 MFMA k-steps over this wave's h-half (k = h*16+b) ----
    f32x4 acc0 = {0.f, 0.f, 0.f, 0.f};
    f32x4 acc1 = {0.f, 0.f, 0.f, 0.f};
    #pragma unroll 2
    for (int ks = 0; ks < 25; ++ks) {
        int hp = wk * 25 + ks;               // h-pair index 0..49
        int h0 = 2 * hp, h1 = h0 + 1;
        float u00 = rw1s[h0],       u01 = rw1s[h1];
        float u10 = rw1s[100 + h0], u11 = rw1s[100 + h1];
        float u20 = rw1s[200 + h0], u21 = rw1s[200 + h1];
        bf16x8 af;
        #pragma unroll
        for (int e = 0; e < 4; ++e) {
            float p0 = bas[e][0] * u00 + bas[e][1] * u10 + bas[e][2] * u20;
            float p1 = bas[e][0] * u01 + bas[e][1] * u11 + bas[e][2] * u21;
            float s0 = p0 * __builtin_amdgcn_rcpf(1.f + __expf(-p0));   // swish
            float s1 = p1 * __builtin_amdgcn_rcpf(1.f + __expf(-p1));
            af[e]     = (__bf16)s0;    // k = lg*4+e      (h0, even)
            af[e + 4] = (__bf16)s1;    // k = lg*4+e+16   (h1, odd)
        }
        int kb = hp * 32 + lg * 4;
        const __bf16* w0 = &Wlds[l16 * WSTR + kb];
        const __bf16* w1 = w0 + 16 * WSTR;
        bf16x4 b0l = *(const bf16x4*)w0, b0h = *(const bf16x4*)(w0 + 16);
        bf16x4 b1l = *(const bf16x4*)w1, b1h = *(const bf16x4*)(w1 + 16);
        bf16x8 bf0 = __builtin_shufflevector(b0l, b0h, 0, 1, 2, 3, 4, 5, 6, 7);
        bf16x8 bf1 = __builtin_shufflevector(b1l, b1h, 0, 1, 2, 3, 4, 5, 6, 7);
        acc0 = __builtin_amdgcn_mfma_f32_16x16x32_bf16(af, bf0, acc0, 0, 0, 0);
        acc1 = __builtin_amdgcn_mfma_f32_16x16x32_bf16(af, bf1, acc1, 0, 0, 0);
    }

    // ---- epilogue: combine wk halves via LDS, atomicAdd into part[z][a][i] ----
    if (wk == 1) {
        #pragma unroll
        for (int r = 0; r < 4; ++r) {
            red[wa][0][lg * 4 + r][l16] = acc0[r];
            red[wa][1][lg * 4 + r][l16] = acc1[r];
        }
    }
    __syncthreads();
    if (wk == 0) {
        #pragma unroll
        for (int r = 0; r < 4; ++r) {
            float v0 = acc0[r] + red[wa][0][lg * 4 + r][l16];
            float v1 = acc1[r] + red[wa][1][lg * 4 + r][l16];
            int a = ac * 64 + wa * 16 + lg * 4 + r;
            float* cell = &part[(size_t)(z * 256 + a) * 32];
            atomicAdd(cell + l16,      v0);
            atomicAdd(cell + 16 + l16, v1);
        }
    }
}

// ---------------------------------------------------------------------------
// K3: one block per z (grid 4, 256 threads). Reads part[z] (32 KB),
// abs+mask+scale, pool over a, normalize (ddof=1), fc3+leaky, fc2 -> out[z].
// ---------------------------------------------------------------------------
__global__ __launch_bounds__(256) void k3_final(const float* __restrict__ part,
                                                const int* __restrict__ mask,
                                                const float* __restrict__ fc3_w,
                                                const float* __restrict__ fc3_b,
                                                const float* __restrict__ fc2_w,
                                                const float* __restrict__ fc2_b,
                                                float* __restrict__ out) {
    __shared__ float pool[8][33];
    __shared__ float pn[32];
    int z = blockIdx.x;
    int t = threadIdx.x;
    int i = t & 31, g = t >> 5;          // g = 0..7, 32 a's each
    float s = 0.f;
    #pragma unroll 8
    for (int al = 0; al < 32; ++al) {
        int a = g * 32 + al;
        float v = part[(size_t)(z * 256 + a) * 32 + i];
        float sc = (mask[z * 256 + a] != 0) ? 0.0625f : 0.f;   // 1/sqrt(256)
        s += fabsf(v) * sc;
    }
    pool[g][i] = s;
    __syncthreads();
    if (t < 32) {
        float p = 0.f;
        #pragma unroll
        for (int q = 0; q < 8; ++q) p += pool[q][t];
        float sm = p;
        #pragma unroll
        for (int off = 16; off; off >>= 1) sm += __shfl_xor(sm, off, 32);
        float mean = sm * (1.f / 32.f);
        float d = p - mean;
        float ss = d * d;
        #pragma unroll
        for (int off = 16; off; off >>= 1) ss += __shfl_xor(ss, off, 32);
        float stdv = sqrtf(ss * (1.f / 31.f));   // ddof=1
        pn[t] = d / (stdv + 1e-6f);
    }
    __syncthreads();
    if (t < 32) {
        float h1 = fc3_b[t];
        #pragma unroll
        for (int j = 0; j < 32; ++j) h1 += pn[j] * fc3_w[j * 32 + t];
        h1 = (h1 >= 0.f) ? h1 : 0.01f * h1;
        float y = h1 * fc2_w[t];
        #pragma unroll
        for (int off = 16; off; off >>= 1) y += __shfl_xor(y, off, 32);
        if (t == 0) out[z] = y + fc2_b[0];
    }
}

extern "C" void kernel_launch(void* const* d_in, const int* in_sizes, int n_in,
                              void* d_out, int out_size, void* d_ws, size_t ws_size,
                              hipStream_t stream) {
    const float* x    = (const float*)d_in[0];
    const float* xyz  = (const float*)d_in[1];
    const int*   mask = (const int*)d_in[2];
    const float* rw1  = (const float*)d_in[3];
    const float* rw2  = (const float*)d_in[4];
    const float* fc3w = (const float*)d_in[5];
    const float* fc3b = (const float*)d_in[6];
    const float* fc2w = (const float*)d_in[7];
    const float* fc2b = (const float*)d_in[8];
    float* out = (float*)d_out;

    float* part = (float*)d_ws;          // 4z * 256a * 32i * 4B = 131,072 B

    const int LDS_BYTES = 32 * WSTR * 2 + 1216 + 8704;      // 112,832

    hipMemsetAsync(part, 0, 131072, stream);                // zero accumulator each call
    hipLaunchKernelGGL(k2_fused, dim3(256), dim3(512), LDS_BYTES, stream,
                       x, xyz, rw1, rw2, part);
    hipLaunchKernelGGL(k3_final, dim3(4), dim3(256), 0, stream,
                       part, mask, fc3w, fc3b, fc2w, fc2b, out);
}